// Round 4
// baseline (196.122 us; speedup 1.0000x reference)
//
#include <hip/hip_runtime.h>
#include <stdint.h>

#define TOKENS 8192
#define IN_F   4096
#define OUT_F  4096

#define BM 256
#define BN 256
#define BK 64                 // bytes of K per slice (64 int8)
#define NK (IN_F / BK)        // 64 slices
#define THREADS 512

typedef int v4i __attribute__((ext_vector_type(4)));

#define GLOBAL_AS __attribute__((address_space(1)))
#define LDS_AS    __attribute__((address_space(3)))

// ---------------- pack x: int32 -> int8 ----------------
__global__ __launch_bounds__(256) void pack_x_kernel(const int* __restrict__ x32,
                                                     uint8_t* __restrict__ x8) {
  int t = blockIdx.x * 256 + threadIdx.x;
  const int4 v = ((const int4*)x32)[t];
  uint32_t p = (uint32_t)(v.x & 0xFF)
             | ((uint32_t)(v.y & 0xFF) << 8)
             | ((uint32_t)(v.z & 0xFF) << 16)
             | ((uint32_t)(v.w & 0xFF) << 24);
  ((uint32_t*)x8)[t] = p;
}

// -------- pack + transpose W: int32 [K][N] -> int8 WT [N][K] --------
__global__ __launch_bounds__(256) void packT_w_kernel(const int* __restrict__ w32,
                                                      uint8_t* __restrict__ wt8) {
  int tn = (blockIdx.x & 63) * 64;
  int tk = (blockIdx.x >> 6) * 64;
  int t = threadIdx.x;
  int n  = tn + (t >> 2);
  int k0 = tk + (t & 3) * 16;
  uint32_t words[4];
#pragma unroll
  for (int w = 0; w < 4; ++w) {
    uint32_t acc = 0;
#pragma unroll
    for (int j = 0; j < 4; ++j) {
      int val = w32[(size_t)(k0 + w * 4 + j) * OUT_F + n];
      acc |= (uint32_t)(val & 0xFF) << (8 * j);
    }
    words[w] = acc;
  }
  uint4 o = make_uint4(words[0], words[1], words[2], words[3]);
  *(uint4*)(wt8 + (size_t)n * IN_F + k0) = o;
}

// ---------------- int8 GEMM: 256x256, 4-slot ring, 2-phase/slice template ----------------
__global__ __launch_bounds__(THREADS, 2) void gemm_i8_kernel(const uint8_t* __restrict__ A,
                                                             const uint8_t* __restrict__ BT,
                                                             const int* __restrict__ bias,
                                                             const float* __restrict__ scales,
                                                             int* __restrict__ out) {
  // Ring of 4 K-slices. Slot: A half0 @0, A half1 @8192, B half0 @16384, B half1 @24576.
  __shared__ __align__(16) uint8_t lds[4 * 32768];   // 128 KiB

  const int t    = threadIdx.x;
  const int lane = t & 63;
  const int w    = t >> 6;
  const int wr   = w >> 2;     // 0..1
  const int wc   = w & 3;      // 0..3
  const int fr   = lane & 15;
  const int fq   = lane >> 4;

  // XCD-aware bijective swizzle: 512 blocks, 512 % 8 == 0
  int bid = blockIdx.x;
  int swz = (bid & 7) * 64 + (bid >> 3);
  int bm = swz >> 4;           // 0..31
  int bn = swz & 15;           // 0..15

  // staging: pre-swizzled global source, linear LDS dest (rule #21)
  // chunk involution sigma(l) = l ^ ((l>>3)&7) on 16B chunks within 8KiB half-tile
  const int lsz  = t ^ ((t >> 3) & 7);
  const int srow = lsz >> 2;
  const int scol = (lsz & 3) * 16;
  const size_t gA0 = (size_t)(bm * BM + srow) * IN_F + scol;
  const size_t gA1 = gA0 + (size_t)128 * IN_F;
  const size_t gB0 = (size_t)(bn * BN + srow) * IN_F + scol;
  const size_t gB1 = gB0 + (size_t)128 * IN_F;
  const int ldst = t * 16;

  auto stageA = [&](int j) {   // A halves of slice j
    uint8_t* sb = lds + (j & 3) * 32768;
    const int k0 = j * BK;
    __builtin_amdgcn_global_load_lds((const GLOBAL_AS void*)(A + gA0 + k0),
                                     (LDS_AS void*)(sb + ldst),          16, 0, 0);
    __builtin_amdgcn_global_load_lds((const GLOBAL_AS void*)(A + gA1 + k0),
                                     (LDS_AS void*)(sb + 8192 + ldst),   16, 0, 0);
  };
  auto stageB = [&](int j) {   // B halves of slice j
    uint8_t* sb = lds + (j & 3) * 32768;
    const int k0 = j * BK;
    __builtin_amdgcn_global_load_lds((const GLOBAL_AS void*)(BT + gB0 + k0),
                                     (LDS_AS void*)(sb + 16384 + ldst),  16, 0, 0);
    __builtin_amdgcn_global_load_lds((const GLOBAL_AS void*)(BT + gB1 + k0),
                                     (LDS_AS void*)(sb + 24576 + ldst),  16, 0, 0);
  };

  // fragment read offsets (slot-relative), sigma-swizzled to match staging
  int aoff[8], boff[4];
#pragma unroll
  for (int m = 0; m < 8; ++m) {
    int row = wr * 128 + m * 16 + fr;
    int half = row >> 7, rl = row & 127;
    int b = rl * 64 + fq * 16;
    b ^= ((rl >> 1) & 7) << 4;
    aoff[m] = half * 8192 + b;
  }
#pragma unroll
  for (int n = 0; n < 4; ++n) {
    int row = wc * 64 + n * 16 + fr;
    int half = row >> 7, rl = row & 127;
    int b = rl * 64 + fq * 16;
    b ^= ((rl >> 1) & 7) << 4;
    boff[n] = 16384 + half * 8192 + b;
  }

  v4i acc[8][4];
  const v4i vzero = {0, 0, 0, 0};
#pragma unroll
  for (int m = 0; m < 8; ++m)
#pragma unroll
    for (int n = 0; n < 4; ++n) acc[m][n] = vzero;

  // Prologue: fill 3 slots -> 12 loads in flight per wave.
  stageA(0); stageB(0); stageA(1); stageB(1); stageA(2); stageB(2);

  // Per slice: two template phases.
  // Phase A: vmcnt(VM); bar; ds_read b0..3,a0..3 + stageA(i+3); bar; lgkm0; 16 MFMA (m0-3)
  // Phase B:            bar; ds_read a4..7      + stageB(i+3); bar; lgkm0; 16 MFMA (m4-7)
  // Hazard: slot (i+3)&3 == (i-1)&3 was drained by every wave's lgkmcnt(0) in
  // slice i-1 phase B, which precedes this slice's leading barrier.
#define SLICE(i, VM, DOSTAGE)                                                   \
  asm volatile("s_waitcnt vmcnt(" #VM ")" ::: "memory");                        \
  asm volatile("s_barrier" ::: "memory");                                       \
  {                                                                             \
    const uint8_t* sb = lds + ((i) & 3) * 32768;                                \
    v4i bf[4], af[4], af2[4];                                                   \
    _Pragma("unroll") for (int n = 0; n < 4; ++n)                               \
      bf[n] = *(const v4i*)(sb + boff[n]);                                      \
    _Pragma("unroll") for (int m = 0; m < 4; ++m)                               \
      af[m] = *(const v4i*)(sb + aoff[m]);                                      \
    if (DOSTAGE) stageA((i) + 3);                                               \
    asm volatile("s_barrier" ::: "memory");                                     \
    asm volatile("s_waitcnt lgkmcnt(0)" ::: "memory");                          \
    __builtin_amdgcn_sched_barrier(0);                                          \
    __builtin_amdgcn_s_setprio(1);                                              \
    _Pragma("unroll") for (int m = 0; m < 4; ++m)                               \
      _Pragma("unroll") for (int n = 0; n < 4; ++n)                             \
        acc[m][n] = __builtin_amdgcn_mfma_i32_16x16x64_i8(af[m], bf[n],         \
                                                          acc[m][n], 0, 0, 0); \
    __builtin_amdgcn_s_setprio(0);                                              \
    asm volatile("s_barrier" ::: "memory");                                     \
    _Pragma("unroll") for (int m = 0; m < 4; ++m)                               \
      af2[m] = *(const v4i*)(sb + aoff[4 + m]);                                 \
    if (DOSTAGE) stageB((i) + 3);                                               \
    asm volatile("s_barrier" ::: "memory");                                     \
    asm volatile("s_waitcnt lgkmcnt(0)" ::: "memory");                          \
    __builtin_amdgcn_sched_barrier(0);                                          \
    __builtin_amdgcn_s_setprio(1);                                              \
    _Pragma("unroll") for (int m = 0; m < 4; ++m)                               \
      _Pragma("unroll") for (int n = 0; n < 4; ++n)                             \
        acc[4 + m][n] = __builtin_amdgcn_mfma_i32_16x16x64_i8(af2[m], bf[n],    \
                                                      acc[4 + m][n], 0, 0, 0); \
    __builtin_amdgcn_s_setprio(0);                                              \
  }

  for (int i = 0; i < NK - 3; ++i) {
    SLICE(i, 8, true)
  }
  SLICE(NK - 3, 8, false)
  SLICE(NK - 2, 4, false)
  SLICE(NK - 1, 0, false)
#undef SLICE

  // ---- epilogue: (acc + bias) * scale * 20, clip, trunc; int32 out ----
  // C/D layout (16x16): col = lane&15, row = (lane>>4)*4 + r
#pragma unroll
  for (int n = 0; n < 4; ++n) {
    const int gn  = bn * BN + wc * 64 + n * 16 + fr;
    const int bsv = bias[gn];
    const float sc = scales[gn] * 20.0f;
#pragma unroll
    for (int m = 0; m < 8; ++m) {
      const int gm0 = bm * BM + wr * 128 + m * 16 + fq * 4;
#pragma unroll
      for (int r = 0; r < 4; ++r) {
        float g = (float)(acc[m][n][r] + bsv) * sc;
        g = fminf(fmaxf(g, -128.0f), 127.0f);
        out[(size_t)(gm0 + r) * OUT_F + gn] = (int)g;
      }
    }
  }
}

extern "C" void kernel_launch(void* const* d_in, const int* in_sizes, int n_in,
                              void* d_out, int out_size, void* d_ws, size_t ws_size,
                              hipStream_t stream) {
  const int*   x32    = (const int*)d_in[0];
  const int*   w32    = (const int*)d_in[1];
  const int*   bias   = (const int*)d_in[2];
  const float* scales = (const float*)d_in[3];
  int* out = (int*)d_out;

  uint8_t* x8  = (uint8_t*)d_ws;                              // 32 MB
  uint8_t* wt8 = (uint8_t*)d_ws + (size_t)TOKENS * IN_F;      // 16 MB

  pack_x_kernel<<<(TOKENS * IN_F / 4) / 256, 256, 0, stream>>>(x32, x8);
  packT_w_kernel<<<(OUT_F / 64) * (IN_F / 64), 256, 0, stream>>>(w32, wt8);
  gemm_i8_kernel<<<(TOKENS / BM) * (OUT_F / BN), THREADS, 0, stream>>>(x8, wt8, bias, scales, out);
}